// Round 1
// baseline (683.182 us; speedup 1.0000x reference)
//
#include <hip/hip_runtime.h>
#include <hip/hip_bf16.h>
#include <math.h>

// Problem constants (match reference)
#define ND 128      // feature dim D
#define NH 4        // heads
#define HD 512      // H*D

// ---------------------------------------------------------------------------
// K1: xw = x @ W   [N,128] x [128,512] -> [N,512], fp32 vector ALU.
// 8 rows per block, 256 threads; each thread owns 2 output columns.
// W rows are streamed coalesced (2KB/k); W (256KB) stays L2-resident.
// ---------------------------------------------------------------------------
__global__ __launch_bounds__(256) void gemm_xw(const float* __restrict__ x,
                                               const float* __restrict__ W,
                                               float* __restrict__ xw, int n) {
    __shared__ float xs[8][ND];
    const int row0 = blockIdx.x * 8;
    const int t = threadIdx.x;

    for (int i = t; i < 8 * ND; i += 256) {
        int r = i >> 7, k = i & (ND - 1);
        int row = row0 + r;
        xs[r][k] = (row < n) ? x[(size_t)row * ND + k] : 0.0f;
    }
    __syncthreads();

    float acc[8][2];
#pragma unroll
    for (int r = 0; r < 8; ++r) { acc[r][0] = 0.0f; acc[r][1] = 0.0f; }

    const int j0 = t, j1 = t + 256;
#pragma unroll 4
    for (int k = 0; k < ND; ++k) {
        float w0 = W[(size_t)k * HD + j0];
        float w1 = W[(size_t)k * HD + j1];
#pragma unroll
        for (int r = 0; r < 8; ++r) {
            acc[r][0] = fmaf(xs[r][k], w0, acc[r][0]);
            acc[r][1] = fmaf(xs[r][k], w1, acc[r][1]);
        }
    }

#pragma unroll
    for (int r = 0; r < 8; ++r) {
        int row = row0 + r;
        if (row < n) {
            xw[(size_t)row * HD + j0] = acc[r][0];
            xw[(size_t)row * HD + j1] = acc[r][1];
        }
    }
}

// ---------------------------------------------------------------------------
// K2: per-(node,head) attention dots. One wave per (n,h).
// a_src[n*4+h] = dot(xw[n,h,:], att_src[h,:]); same for a_dst.
// ---------------------------------------------------------------------------
__global__ __launch_bounds__(256) void compute_ah(const float* __restrict__ xw,
                                                  const float* __restrict__ att_src,
                                                  const float* __restrict__ att_dst,
                                                  float* __restrict__ a_src,
                                                  float* __restrict__ a_dst, int n) {
    int wave = (blockIdx.x * 256 + threadIdx.x) >> 6;
    int lane = threadIdx.x & 63;
    if (wave >= n * NH) return;
    int node = wave >> 2, h = wave & 3;

    const float* p = xw + (size_t)node * HD + h * ND;
    float v0 = p[lane], v1 = p[lane + 64];
    float as0 = att_src[h * ND + lane], as1 = att_src[h * ND + lane + 64];
    float ad0 = att_dst[h * ND + lane], ad1 = att_dst[h * ND + lane + 64];
    float s = v0 * as0 + v1 * as1;
    float d = v0 * ad0 + v1 * ad1;
#pragma unroll
    for (int off = 32; off; off >>= 1) {
        s += __shfl_down(s, off);
        d += __shfl_down(d, off);
    }
    if (lane == 0) { a_src[wave] = s; a_dst[wave] = d; }
}

// ---------------------------------------------------------------------------
// K3: edge pass 1 — softmax denominators (max-subtraction skipped; fp32 exp is
// safe for |alpha| up to ~80, we have ~10 max).
// One thread per edge; 4 fp32 atomics onto an 800KB L2-resident table.
// ---------------------------------------------------------------------------
__global__ __launch_bounds__(256) void edge_denom(const int* __restrict__ src,
                                                  const int* __restrict__ dst,
                                                  const float* __restrict__ a_src,
                                                  const float* __restrict__ a_dst,
                                                  float* __restrict__ denom, int ne) {
    int e = blockIdx.x * 256 + threadIdx.x;
    if (e >= ne) return;
    int s = src[e], t = dst[e];
    float4 as = *(const float4*)(a_src + (size_t)s * NH);
    float4 ad = *(const float4*)(a_dst + (size_t)t * NH);
    float a0 = as.x + ad.x, a1 = as.y + ad.y, a2 = as.z + ad.z, a3 = as.w + ad.w;
    a0 = (a0 > 0.0f) ? a0 : 0.2f * a0;
    a1 = (a1 > 0.0f) ? a1 : 0.2f * a1;
    a2 = (a2 > 0.0f) ? a2 : 0.2f * a2;
    a3 = (a3 > 0.0f) ? a3 : 0.2f * a3;
    atomicAdd(&denom[(size_t)t * NH + 0], expf(a0));
    atomicAdd(&denom[(size_t)t * NH + 1], expf(a1));
    atomicAdd(&denom[(size_t)t * NH + 2], expf(a2));
    atomicAdd(&denom[(size_t)t * NH + 3], expf(a3));
}

// ---------------------------------------------------------------------------
// K4: edge pass 2 — gather xw[src] row (2KB, L3-resident table), weight by
// attn (1/H folded in), atomicAdd 128 floats into out (=agg accumulator).
// One wave per edge.
// ---------------------------------------------------------------------------
__global__ __launch_bounds__(256) void edge_scatter(const int* __restrict__ src,
                                                    const int* __restrict__ dst,
                                                    const float* __restrict__ a_src,
                                                    const float* __restrict__ a_dst,
                                                    const float* __restrict__ denom,
                                                    const float* __restrict__ xw,
                                                    float* __restrict__ out, int ne) {
    int gid = blockIdx.x * 256 + threadIdx.x;
    int e = gid >> 6;
    int lane = gid & 63;
    if (e >= ne) return;
    int s = src[e], t = dst[e];
    float4 as = *(const float4*)(a_src + (size_t)s * NH);
    float4 ad = *(const float4*)(a_dst + (size_t)t * NH);
    float4 dn = *(const float4*)(denom + (size_t)t * NH);
    float a0 = as.x + ad.x, a1 = as.y + ad.y, a2 = as.z + ad.z, a3 = as.w + ad.w;
    a0 = (a0 > 0.0f) ? a0 : 0.2f * a0;
    a1 = (a1 > 0.0f) ? a1 : 0.2f * a1;
    a2 = (a2 > 0.0f) ? a2 : 0.2f * a2;
    a3 = (a3 > 0.0f) ? a3 : 0.2f * a3;
    // attn * (1/H)
    float w0 = 0.25f * expf(a0) / dn.x;
    float w1 = 0.25f * expf(a1) / dn.y;
    float w2 = 0.25f * expf(a2) / dn.z;
    float w3 = 0.25f * expf(a3) / dn.w;

    const float* xr = xw + (size_t)s * HD;
    float v0 = w0 * xr[lane]       + w1 * xr[ND + lane]
             + w2 * xr[2 * ND + lane] + w3 * xr[3 * ND + lane];
    float v1 = w0 * xr[64 + lane]       + w1 * xr[ND + 64 + lane]
             + w2 * xr[2 * ND + 64 + lane] + w3 * xr[3 * ND + 64 + lane];
    atomicAdd(&out[(size_t)t * ND + lane], v0);
    atomicAdd(&out[(size_t)t * ND + 64 + lane], v1);
}

// ---------------------------------------------------------------------------
// K5: finalize per node: +bias, LayerNorm(eps=1e-5), exact GELU, +x residual.
// 128 threads (2 waves) per node, in-place on out.
// ---------------------------------------------------------------------------
__global__ __launch_bounds__(128) void finalize(float* __restrict__ out,
                                                const float* __restrict__ x,
                                                const float* __restrict__ bias,
                                                const float* __restrict__ gamma,
                                                const float* __restrict__ beta, int n) {
    int node = blockIdx.x;
    int t = threadIdx.x;
    float v = out[(size_t)node * ND + t] + bias[t];

    float s = v, s2 = v * v;
#pragma unroll
    for (int off = 32; off; off >>= 1) {
        s += __shfl_down(s, off);
        s2 += __shfl_down(s2, off);
    }
    __shared__ float red[4];
    int wv = t >> 6, ln = t & 63;
    if (ln == 0) { red[wv] = s; red[2 + wv] = s2; }
    __syncthreads();
    float total = red[0] + red[1];
    float total2 = red[2] + red[3];
    float mu = total * (1.0f / ND);
    float var = total2 * (1.0f / ND) - mu * mu;
    var = fmaxf(var, 0.0f);
    float inv = rsqrtf(var + 1e-5f);
    float yn = (v - mu) * inv * gamma[t] + beta[t];
    float g = 0.5f * yn * (1.0f + erff(yn * 0.70710678118654752f));
    out[(size_t)node * ND + t] = g + x[(size_t)node * ND + t];
}

// ---------------------------------------------------------------------------
extern "C" void kernel_launch(void* const* d_in, const int* in_sizes, int n_in,
                              void* d_out, int out_size, void* d_ws, size_t ws_size,
                              hipStream_t stream) {
    const float* x       = (const float*)d_in[0];
    const int*   edge    = (const int*)d_in[1];   // [2, E]: src row then dst row
    const float* W       = (const float*)d_in[2];
    const float* att_src = (const float*)d_in[3];
    const float* att_dst = (const float*)d_in[4];
    const float* bias    = (const float*)d_in[5];
    const float* gamma   = (const float*)d_in[6];
    const float* beta    = (const float*)d_in[7];
    float* out = (float*)d_out;

    const int n  = in_sizes[0] / ND;   // 50000
    const int ne = in_sizes[1] / 2;    // 800000
    const int* src = edge;
    const int* dst = edge + ne;

    float* ws     = (float*)d_ws;
    float* xw     = ws;                          // n*512
    float* a_src  = xw + (size_t)n * HD;         // n*4
    float* a_dst  = a_src + (size_t)n * NH;      // n*4
    float* denom  = a_dst + (size_t)n * NH;      // n*4

    hipMemsetAsync(denom, 0, (size_t)n * NH * sizeof(float), stream);
    hipMemsetAsync(out, 0, (size_t)n * ND * sizeof(float), stream);

    gemm_xw<<<(n + 7) / 8, 256, 0, stream>>>(x, W, xw, n);
    compute_ah<<<n, 256, 0, stream>>>(xw, att_src, att_dst, a_src, a_dst, n);
    edge_denom<<<(ne + 255) / 256, 256, 0, stream>>>(src, dst, a_src, a_dst, denom, ne);
    edge_scatter<<<(ne * 64 + 255) / 256, 256, 0, stream>>>(src, dst, a_src, a_dst,
                                                            denom, xw, out, ne);
    finalize<<<n, ND, 0, stream>>>(out, x, bias, gamma, beta, n);
}

// Round 2
// 489.325 us; speedup vs baseline: 1.3962x; 1.3962x over previous
//
#include <hip/hip_runtime.h>
#include <hip/hip_bf16.h>
#include <math.h>

#define ND 128      // feature dim D
#define NH 4        // heads
#define HD 512      // H*D

// ---------------------------------------------------------------------------
// K1: xw = x @ W   [N,128] x [128,512] -> [N,512], fp32 vector ALU.
// 16 rows per block, 256 threads; each thread owns 2 output columns.
// ---------------------------------------------------------------------------
__global__ __launch_bounds__(256) void gemm_xw(const float* __restrict__ x,
                                               const float* __restrict__ W,
                                               float* __restrict__ xw, int n) {
    __shared__ float xs[16][ND];
    const int row0 = blockIdx.x * 16;
    const int t = threadIdx.x;

    for (int i = t; i < 16 * ND; i += 256) {
        int r = i >> 7, k = i & (ND - 1);
        int row = row0 + r;
        xs[r][k] = (row < n) ? x[(size_t)row * ND + k] : 0.0f;
    }
    __syncthreads();

    float acc[16][2];
#pragma unroll
    for (int r = 0; r < 16; ++r) { acc[r][0] = 0.0f; acc[r][1] = 0.0f; }

    const int j0 = t, j1 = t + 256;
#pragma unroll 4
    for (int k = 0; k < ND; ++k) {
        float w0 = W[(size_t)k * HD + j0];
        float w1 = W[(size_t)k * HD + j1];
#pragma unroll
        for (int r = 0; r < 16; ++r) {
            acc[r][0] = fmaf(xs[r][k], w0, acc[r][0]);
            acc[r][1] = fmaf(xs[r][k], w1, acc[r][1]);
        }
    }

#pragma unroll
    for (int r = 0; r < 16; ++r) {
        int row = row0 + r;
        if (row < n) {
            xw[(size_t)row * HD + j0] = acc[r][0];
            xw[(size_t)row * HD + j1] = acc[r][1];
        }
    }
}

// ---------------------------------------------------------------------------
// K2: per-(node,head) attention dots. One wave per (n,h).
// ---------------------------------------------------------------------------
__global__ __launch_bounds__(256) void compute_ah(const float* __restrict__ xw,
                                                  const float* __restrict__ att_src,
                                                  const float* __restrict__ att_dst,
                                                  float* __restrict__ a_src,
                                                  float* __restrict__ a_dst, int n) {
    int wave = (blockIdx.x * 256 + threadIdx.x) >> 6;
    int lane = threadIdx.x & 63;
    if (wave >= n * NH) return;
    int node = wave >> 2, h = wave & 3;

    const float* p = xw + (size_t)node * HD + h * ND;
    float v0 = p[lane], v1 = p[lane + 64];
    float as0 = att_src[h * ND + lane], as1 = att_src[h * ND + lane + 64];
    float ad0 = att_dst[h * ND + lane], ad1 = att_dst[h * ND + lane + 64];
    float s = v0 * as0 + v1 * as1;
    float d = v0 * ad0 + v1 * ad1;
#pragma unroll
    for (int off = 32; off; off >>= 1) {
        s += __shfl_down(s, off);
        d += __shfl_down(d, off);
    }
    if (lane == 0) { a_src[wave] = s; a_dst[wave] = d; }
}

// ---------------------------------------------------------------------------
// Counting sort of edges by dst: hist -> scan (3 kernels) -> scatter.
// ---------------------------------------------------------------------------
__global__ __launch_bounds__(256) void hist_dst(const int* __restrict__ dst,
                                                int* __restrict__ cnt, int ne) {
    int e = blockIdx.x * 256 + threadIdx.x;
    if (e < ne) atomicAdd(&cnt[dst[e]], 1);
}

__global__ __launch_bounds__(256) void scanA(const int* __restrict__ cnt,
                                             int* __restrict__ partial,
                                             int* __restrict__ bsum, int n) {
    __shared__ int sh[256];
    int gid = blockIdx.x * 256 + threadIdx.x;
    int v = (gid < n) ? cnt[gid] : 0;
    int val = v;
    sh[threadIdx.x] = val;
    __syncthreads();
#pragma unroll
    for (int off = 1; off < 256; off <<= 1) {
        int add = (threadIdx.x >= off) ? sh[threadIdx.x - off] : 0;
        __syncthreads();
        val += add;
        sh[threadIdx.x] = val;
        __syncthreads();
    }
    if (gid < n) partial[gid] = val - v;     // exclusive within block
    if (threadIdx.x == 255) bsum[blockIdx.x] = val;  // block total
}

__global__ __launch_bounds__(256) void scanB(int* __restrict__ bsum, int nb) {
    __shared__ int sh[256];
    int t = threadIdx.x;
    int v = (t < nb) ? bsum[t] : 0;
    int val = v;
    sh[t] = val;
    __syncthreads();
#pragma unroll
    for (int off = 1; off < 256; off <<= 1) {
        int add = (t >= off) ? sh[t - off] : 0;
        __syncthreads();
        val += add;
        sh[t] = val;
        __syncthreads();
    }
    if (t < nb) bsum[t] = val - v;           // exclusive
}

__global__ __launch_bounds__(256) void scanC(const int* __restrict__ partial,
                                             const int* __restrict__ bsum,
                                             int* __restrict__ starts,
                                             int* __restrict__ cursor, int n, int ne) {
    int gid = blockIdx.x * 256 + threadIdx.x;
    if (gid < n) {
        int s = partial[gid] + bsum[blockIdx.x];
        starts[gid] = s;
        cursor[gid] = s;
    }
    if (gid == 0) starts[n] = ne;
}

__global__ __launch_bounds__(256) void scatter_edges(const int* __restrict__ src,
                                                     const int* __restrict__ dst,
                                                     int* __restrict__ cursor,
                                                     int* __restrict__ srcperm, int ne) {
    int e = blockIdx.x * 256 + threadIdx.x;
    if (e < ne) {
        int pos = atomicAdd(&cursor[dst[e]], 1);
        srcperm[pos] = src[e];
    }
}

// ---------------------------------------------------------------------------
// K_agg: one wave per dst node. Single pass over its edges with deferred
// normalization (per-head partial sums), fused bias+LN+GELU+residual.
// ---------------------------------------------------------------------------
__global__ __launch_bounds__(256) void node_agg(const int* __restrict__ srcperm,
                                                const int* __restrict__ starts,
                                                const float* __restrict__ a_src,
                                                const float* __restrict__ a_dst,
                                                const float* __restrict__ xw,
                                                const float* __restrict__ x,
                                                const float* __restrict__ bias,
                                                const float* __restrict__ gamma,
                                                const float* __restrict__ beta,
                                                float* __restrict__ out, int n) {
    int node = (blockIdx.x * 256 + threadIdx.x) >> 6;
    int lane = threadIdx.x & 63;
    if (node >= n) return;

    int s0 = starts[node], s1 = starts[node + 1];
    float4 ad = *(const float4*)(a_dst + (size_t)node * NH);

    float den0 = 0.f, den1 = 0.f, den2 = 0.f, den3 = 0.f;
    float a00 = 0.f, a01 = 0.f, a10 = 0.f, a11 = 0.f;
    float a20 = 0.f, a21 = 0.f, a30 = 0.f, a31 = 0.f;

    for (int base = s0; base < s1; base += 64) {
        int rem = s1 - base; if (rem > 64) rem = 64;
        int s_l = 0;
        float e0 = 0.f, e1 = 0.f, e2 = 0.f, e3 = 0.f;
        if (lane < rem) {
            s_l = srcperm[base + lane];
            float4 as = *(const float4*)(a_src + (size_t)s_l * NH);
            float A0 = as.x + ad.x, A1 = as.y + ad.y, A2 = as.z + ad.z, A3 = as.w + ad.w;
            A0 = (A0 > 0.f) ? A0 : 0.2f * A0;
            A1 = (A1 > 0.f) ? A1 : 0.2f * A1;
            A2 = (A2 > 0.f) ? A2 : 0.2f * A2;
            A3 = (A3 > 0.f) ? A3 : 0.2f * A3;
            e0 = expf(A0); e1 = expf(A1); e2 = expf(A2); e3 = expf(A3);
            den0 += e0; den1 += e1; den2 += e2; den3 += e3;
        }
        for (int j = 0; j < rem; ++j) {
            int s = __shfl(s_l, j);
            float w0 = __shfl(e0, j), w1 = __shfl(e1, j);
            float w2 = __shfl(e2, j), w3 = __shfl(e3, j);
            const float* xr = xw + (size_t)s * HD;
            a00 = fmaf(w0, xr[lane], a00);
            a01 = fmaf(w0, xr[64 + lane], a01);
            a10 = fmaf(w1, xr[ND + lane], a10);
            a11 = fmaf(w1, xr[ND + 64 + lane], a11);
            a20 = fmaf(w2, xr[2 * ND + lane], a20);
            a21 = fmaf(w2, xr[2 * ND + 64 + lane], a21);
            a30 = fmaf(w3, xr[3 * ND + lane], a30);
            a31 = fmaf(w3, xr[3 * ND + 64 + lane], a31);
        }
    }

    // wave-allreduce the 4 denominators
#pragma unroll
    for (int off = 1; off < 64; off <<= 1) {
        den0 += __shfl_xor(den0, off);
        den1 += __shfl_xor(den1, off);
        den2 += __shfl_xor(den2, off);
        den3 += __shfl_xor(den3, off);
    }
    float i0 = (den0 > 0.f) ? 0.25f / den0 : 0.f;
    float i1 = (den1 > 0.f) ? 0.25f / den1 : 0.f;
    float i2 = (den2 > 0.f) ? 0.25f / den2 : 0.f;
    float i3 = (den3 > 0.f) ? 0.25f / den3 : 0.f;

    float v0 = a00 * i0 + a10 * i1 + a20 * i2 + a30 * i3 + bias[lane];
    float v1 = a01 * i0 + a11 * i1 + a21 * i2 + a31 * i3 + bias[64 + lane];

    // LayerNorm over 128 (2 vals per lane), wave allreduce
    float s = v0 + v1, s2 = v0 * v0 + v1 * v1;
#pragma unroll
    for (int off = 1; off < 64; off <<= 1) {
        s += __shfl_xor(s, off);
        s2 += __shfl_xor(s2, off);
    }
    float mu = s * (1.0f / ND);
    float var = s2 * (1.0f / ND) - mu * mu;
    var = fmaxf(var, 0.0f);
    float inv = rsqrtf(var + 1e-5f);

    float y0 = (v0 - mu) * inv * gamma[lane] + beta[lane];
    float y1 = (v1 - mu) * inv * gamma[64 + lane] + beta[64 + lane];
    float g0 = 0.5f * y0 * (1.0f + erff(y0 * 0.70710678118654752f));
    float g1 = 0.5f * y1 * (1.0f + erff(y1 * 0.70710678118654752f));

    out[(size_t)node * ND + lane]      = g0 + x[(size_t)node * ND + lane];
    out[(size_t)node * ND + 64 + lane] = g1 + x[(size_t)node * ND + 64 + lane];
}

// ---------------------------------------------------------------------------
extern "C" void kernel_launch(void* const* d_in, const int* in_sizes, int n_in,
                              void* d_out, int out_size, void* d_ws, size_t ws_size,
                              hipStream_t stream) {
    const float* x       = (const float*)d_in[0];
    const int*   edge    = (const int*)d_in[1];   // [2, E]: src row then dst row
    const float* W       = (const float*)d_in[2];
    const float* att_src = (const float*)d_in[3];
    const float* att_dst = (const float*)d_in[4];
    const float* bias    = (const float*)d_in[5];
    const float* gamma   = (const float*)d_in[6];
    const float* beta    = (const float*)d_in[7];
    float* out = (float*)d_out;

    const int n  = in_sizes[0] / ND;   // 50000
    const int ne = in_sizes[1] / 2;    // 800000
    const int* src = edge;
    const int* dst = edge + ne;

    const int nb = (n + 255) / 256;    // scan blocks (196)

    char* w = (char*)d_ws;
    float* xw      = (float*)w;                 w += (size_t)n * HD * sizeof(float);
    float* a_src   = (float*)w;                 w += (size_t)n * NH * sizeof(float);
    float* a_dst   = (float*)w;                 w += (size_t)n * NH * sizeof(float);
    int*   cnt     = (int*)w;                   w += (size_t)n * sizeof(int);
    int*   partial = (int*)w;                   w += (size_t)n * sizeof(int);
    int*   bsum    = (int*)w;                   w += 256 * sizeof(int);
    int*   starts  = (int*)w;                   w += (size_t)(n + 1) * sizeof(int);
    int*   cursor  = (int*)w;                   w += (size_t)n * sizeof(int);
    int*   srcperm = (int*)w;                   w += (size_t)ne * sizeof(int);

    hipMemsetAsync(cnt, 0, (size_t)n * sizeof(int), stream);

    gemm_xw<<<(n + 15) / 16, 256, 0, stream>>>(x, W, xw, n);
    compute_ah<<<n, 256, 0, stream>>>(xw, att_src, att_dst, a_src, a_dst, n);

    hist_dst<<<(ne + 255) / 256, 256, 0, stream>>>(dst, cnt, ne);
    scanA<<<nb, 256, 0, stream>>>(cnt, partial, bsum, n);
    scanB<<<1, 256, 0, stream>>>(bsum, nb);
    scanC<<<nb, 256, 0, stream>>>(partial, bsum, starts, cursor, n, ne);
    scatter_edges<<<(ne + 255) / 256, 256, 0, stream>>>(src, dst, cursor, srcperm, ne);

    node_agg<<<(n * 64 + 255) / 256, 256, 0, stream>>>(srcperm, starts, a_src, a_dst,
                                                       xw, x, bias, gamma, beta, out, n);
}

// Round 3
// 339.277 us; speedup vs baseline: 2.0136x; 1.4423x over previous
//
#include <hip/hip_runtime.h>
#include <hip/hip_bf16.h>
#include <math.h>

#define ND 128      // feature dim D
#define NH 4        // heads
#define HD 512      // H*D

__device__ __forceinline__ unsigned pack_bf16(float a, float b) {
    unsigned ua = __float_as_uint(a), ub = __float_as_uint(b);
    ua = (ua + 0x7fffu + ((ua >> 16) & 1u)) >> 16;
    ub = (ub + 0x7fffu + ((ub >> 16) & 1u)) >> 16;
    return ua | (ub << 16);
}
__device__ __forceinline__ float bflo(unsigned u) { return __uint_as_float(u << 16); }
__device__ __forceinline__ float bfhi(unsigned u) { return __uint_as_float(u & 0xffff0000u); }

// ---------------------------------------------------------------------------
// K1: xw = x @ W -> bf16 [N,512], plus fused per-head attention dots in fp32.
// 16 rows/block, 256 threads; thread t owns adjacent cols (2t, 2t+1) so the
// bf16 store is one packed uint and W loads are float2. Wave w owns exactly
// head w's 128 columns -> wave shfl-reduce gives a_src/a_dst.
// ---------------------------------------------------------------------------
__global__ __launch_bounds__(256) void gemm_xw_fused(const float* __restrict__ x,
                                                     const float* __restrict__ W,
                                                     const float* __restrict__ att_src,
                                                     const float* __restrict__ att_dst,
                                                     unsigned* __restrict__ xw,  // packed bf16x2
                                                     float* __restrict__ a_src,
                                                     float* __restrict__ a_dst, int n) {
    __shared__ float xs[16][ND];
    const int row0 = blockIdx.x * 16;
    const int t = threadIdx.x;

    for (int i = t; i < 16 * ND; i += 256) {
        int r = i >> 7, k = i & (ND - 1);
        int row = row0 + r;
        xs[r][k] = (row < n) ? x[(size_t)row * ND + k] : 0.0f;
    }
    __syncthreads();

    float acc0[16], acc1[16];
#pragma unroll
    for (int r = 0; r < 16; ++r) { acc0[r] = 0.0f; acc1[r] = 0.0f; }

#pragma unroll 4
    for (int k = 0; k < ND; ++k) {
        float2 w = ((const float2*)(W + (size_t)k * HD))[t];
#pragma unroll
        for (int r = 0; r < 16; ++r) {
            acc0[r] = fmaf(xs[r][k], w.x, acc0[r]);
            acc1[r] = fmaf(xs[r][k], w.y, acc1[r]);
        }
    }

#pragma unroll
    for (int r = 0; r < 16; ++r) {
        int row = row0 + r;
        if (row < n) xw[(size_t)row * 256 + t] = pack_bf16(acc0[r], acc1[r]);
    }

    // fused attention dots: wave w == head w; local col pair = (2*(t&63), +1)
    const int wv = t >> 6, ln = t & 63;
    float2 asv = *(const float2*)(att_src + wv * ND + 2 * ln);
    float2 adv = *(const float2*)(att_dst + wv * ND + 2 * ln);
#pragma unroll
    for (int r = 0; r < 16; ++r) {
        float cs = acc0[r] * asv.x + acc1[r] * asv.y;
        float cd = acc0[r] * adv.x + acc1[r] * adv.y;
#pragma unroll
        for (int off = 32; off; off >>= 1) {
            cs += __shfl_down(cs, off);
            cd += __shfl_down(cd, off);
        }
        int row = row0 + r;
        if (ln == 0 && row < n) {
            a_src[(size_t)row * NH + wv] = cs;
            a_dst[(size_t)row * NH + wv] = cd;
        }
    }
}

// ---------------------------------------------------------------------------
// Counting sort of edges by dst: hist -> scan (3 kernels) -> scatter.
// ---------------------------------------------------------------------------
__global__ __launch_bounds__(256) void hist_dst(const int* __restrict__ dst,
                                                int* __restrict__ cnt, int ne) {
    int e = blockIdx.x * 256 + threadIdx.x;
    if (e < ne) atomicAdd(&cnt[dst[e]], 1);
}

__global__ __launch_bounds__(256) void scanA(const int* __restrict__ cnt,
                                             int* __restrict__ partial,
                                             int* __restrict__ bsum, int n) {
    __shared__ int sh[256];
    int gid = blockIdx.x * 256 + threadIdx.x;
    int v = (gid < n) ? cnt[gid] : 0;
    int val = v;
    sh[threadIdx.x] = val;
    __syncthreads();
#pragma unroll
    for (int off = 1; off < 256; off <<= 1) {
        int add = (threadIdx.x >= off) ? sh[threadIdx.x - off] : 0;
        __syncthreads();
        val += add;
        sh[threadIdx.x] = val;
        __syncthreads();
    }
    if (gid < n) partial[gid] = val - v;
    if (threadIdx.x == 255) bsum[blockIdx.x] = val;
}

__global__ __launch_bounds__(256) void scanB(int* __restrict__ bsum, int nb) {
    __shared__ int sh[256];
    int t = threadIdx.x;
    int v = (t < nb) ? bsum[t] : 0;
    int val = v;
    sh[t] = val;
    __syncthreads();
#pragma unroll
    for (int off = 1; off < 256; off <<= 1) {
        int add = (t >= off) ? sh[t - off] : 0;
        __syncthreads();
        val += add;
        sh[t] = val;
        __syncthreads();
    }
    if (t < nb) bsum[t] = val - v;
}

__global__ __launch_bounds__(256) void scanC(const int* __restrict__ partial,
                                             const int* __restrict__ bsum,
                                             int* __restrict__ starts,
                                             int* __restrict__ cursor, int n, int ne) {
    int gid = blockIdx.x * 256 + threadIdx.x;
    if (gid < n) {
        int s = partial[gid] + bsum[blockIdx.x];
        starts[gid] = s;
        cursor[gid] = s;
    }
    if (gid == 0) starts[n] = ne;
}

__global__ __launch_bounds__(256) void scatter_edges(const int* __restrict__ src,
                                                     const int* __restrict__ dst,
                                                     int* __restrict__ cursor,
                                                     int* __restrict__ srcperm, int ne) {
    int e = blockIdx.x * 256 + threadIdx.x;
    if (e < ne) {
        int pos = atomicAdd(&cursor[dst[e]], 1);
        srcperm[pos] = src[e];
    }
}

// ---------------------------------------------------------------------------
// K_agg: one wave per dst node. bf16 xw gather: one dwordx4 per lane per edge
// (lane/16 = head, lane%16 = feature octet). Deferred softmax normalization,
// fused head-mean + bias + LN + GELU + residual.
// ---------------------------------------------------------------------------
__global__ __launch_bounds__(256) void node_agg(const int* __restrict__ srcperm,
                                                const int* __restrict__ starts,
                                                const float* __restrict__ a_src,
                                                const float* __restrict__ a_dst,
                                                const uint4* __restrict__ xw,
                                                const float* __restrict__ x,
                                                const float* __restrict__ bias,
                                                const float* __restrict__ gamma,
                                                const float* __restrict__ beta,
                                                float* __restrict__ out, int n) {
    int node = (blockIdx.x * 256 + threadIdx.x) >> 6;
    int lane = threadIdx.x & 63;
    if (node >= n) return;
    const int hgrp = lane >> 4;   // my head
    const int fid = lane & 15;    // my feature octet

    int s0 = starts[node], s1 = starts[node + 1];
    float4 ad = *(const float4*)(a_dst + (size_t)node * NH);

    float den0 = 0.f, den1 = 0.f, den2 = 0.f, den3 = 0.f;
    float acc[8];
#pragma unroll
    for (int j = 0; j < 8; ++j) acc[j] = 0.f;

    for (int base = s0; base < s1; base += 64) {
        int rem = s1 - base; if (rem > 64) rem = 64;
        int s_l = 0;
        float e0 = 0.f, e1 = 0.f, e2 = 0.f, e3 = 0.f;
        if (lane < rem) {
            s_l = srcperm[base + lane];
            float4 as = *(const float4*)(a_src + (size_t)s_l * NH);
            float A0 = as.x + ad.x, A1 = as.y + ad.y, A2 = as.z + ad.z, A3 = as.w + ad.w;
            A0 = (A0 > 0.f) ? A0 : 0.2f * A0;
            A1 = (A1 > 0.f) ? A1 : 0.2f * A1;
            A2 = (A2 > 0.f) ? A2 : 0.2f * A2;
            A3 = (A3 > 0.f) ? A3 : 0.2f * A3;
            e0 = expf(A0); e1 = expf(A1); e2 = expf(A2); e3 = expf(A3);
            den0 += e0; den1 += e1; den2 += e2; den3 += e3;
        }
        for (int j = 0; j < rem; ++j) {
            int s = __shfl(s_l, j);
            float w0 = __shfl(e0, j), w1 = __shfl(e1, j);
            float w2 = __shfl(e2, j), w3 = __shfl(e3, j);
            float wmy = (hgrp == 0) ? w0 : (hgrp == 1) ? w1 : (hgrp == 2) ? w2 : w3;
            uint4 v = xw[(size_t)s * 64 + lane];
            acc[0] = fmaf(wmy, bflo(v.x), acc[0]);
            acc[1] = fmaf(wmy, bfhi(v.x), acc[1]);
            acc[2] = fmaf(wmy, bflo(v.y), acc[2]);
            acc[3] = fmaf(wmy, bfhi(v.y), acc[3]);
            acc[4] = fmaf(wmy, bflo(v.z), acc[4]);
            acc[5] = fmaf(wmy, bfhi(v.z), acc[5]);
            acc[6] = fmaf(wmy, bflo(v.w), acc[6]);
            acc[7] = fmaf(wmy, bfhi(v.w), acc[7]);
        }
    }

    // denominator allreduce
#pragma unroll
    for (int off = 1; off < 64; off <<= 1) {
        den0 += __shfl_xor(den0, off);
        den1 += __shfl_xor(den1, off);
        den2 += __shfl_xor(den2, off);
        den3 += __shfl_xor(den3, off);
    }
    float i0 = (den0 > 0.f) ? 0.25f / den0 : 0.f;
    float i1 = (den1 > 0.f) ? 0.25f / den1 : 0.f;
    float i2 = (den2 > 0.f) ? 0.25f / den2 : 0.f;
    float i3 = (den3 > 0.f) ? 0.25f / den3 : 0.f;
    float imy = (hgrp == 0) ? i0 : (hgrp == 1) ? i1 : (hgrp == 2) ? i2 : i3;

    float v[8];
#pragma unroll
    for (int j = 0; j < 8; ++j) {
        v[j] = acc[j] * imy;
        v[j] += __shfl_xor(v[j], 16);   // sum over heads
        v[j] += __shfl_xor(v[j], 32);
    }

    const float4* bp = (const float4*)(bias + fid * 8);
    float4 b0 = bp[0], b1 = bp[1];
    v[0] += b0.x; v[1] += b0.y; v[2] += b0.z; v[3] += b0.w;
    v[4] += b1.x; v[5] += b1.y; v[6] += b1.z; v[7] += b1.w;

    // LayerNorm over 128 features = 16 lane-groups x 8 slots (replicated 4x)
    float s = 0.f, s2 = 0.f;
#pragma unroll
    for (int j = 0; j < 8; ++j) { s += v[j]; s2 += v[j] * v[j]; }
#pragma unroll
    for (int off = 1; off < 16; off <<= 1) {
        s += __shfl_xor(s, off);
        s2 += __shfl_xor(s2, off);
    }
    float mu = s * (1.0f / ND);
    float var = s2 * (1.0f / ND) - mu * mu;
    var = fmaxf(var, 0.0f);
    float inv = rsqrtf(var + 1e-5f);

    const float4* gp = (const float4*)(gamma + fid * 8);
    const float4* btp = (const float4*)(beta + fid * 8);
    float4 g0 = gp[0], g1 = gp[1];
    float4 t0 = btp[0], t1 = btp[1];
    float gm[8] = {g0.x, g0.y, g0.z, g0.w, g1.x, g1.y, g1.z, g1.w};
    float bt[8] = {t0.x, t0.y, t0.z, t0.w, t1.x, t1.y, t1.z, t1.w};

    float y[8];
#pragma unroll
    for (int j = 0; j < 8; ++j) {
        float yn = (v[j] - mu) * inv * gm[j] + bt[j];
        y[j] = 0.5f * yn * (1.0f + erff(yn * 0.70710678118654752f));
    }

    if (lane < 16) {   // one replica writes; +residual
        const float4* xp = (const float4*)(x + (size_t)node * ND + fid * 8);
        float4 r0 = xp[0], r1 = xp[1];
        float4 o0 = {y[0] + r0.x, y[1] + r0.y, y[2] + r0.z, y[3] + r0.w};
        float4 o1 = {y[4] + r1.x, y[5] + r1.y, y[6] + r1.z, y[7] + r1.w};
        float4* op = (float4*)(out + (size_t)node * ND + fid * 8);
        op[0] = o0; op[1] = o1;
    }
}

// ---------------------------------------------------------------------------
extern "C" void kernel_launch(void* const* d_in, const int* in_sizes, int n_in,
                              void* d_out, int out_size, void* d_ws, size_t ws_size,
                              hipStream_t stream) {
    const float* x       = (const float*)d_in[0];
    const int*   edge    = (const int*)d_in[1];   // [2, E]: src row then dst row
    const float* W       = (const float*)d_in[2];
    const float* att_src = (const float*)d_in[3];
    const float* att_dst = (const float*)d_in[4];
    const float* bias    = (const float*)d_in[5];
    const float* gamma   = (const float*)d_in[6];
    const float* beta    = (const float*)d_in[7];
    float* out = (float*)d_out;

    const int n  = in_sizes[0] / ND;   // 50000
    const int ne = in_sizes[1] / 2;    // 800000
    const int* src = edge;
    const int* dst = edge + ne;

    const int nb = (n + 255) / 256;    // scan blocks (196 <= 256)

    char* w = (char*)d_ws;
    unsigned* xw   = (unsigned*)w;              w += (size_t)n * 256 * sizeof(unsigned); // bf16x2
    float* a_src   = (float*)w;                 w += (size_t)n * NH * sizeof(float);
    float* a_dst   = (float*)w;                 w += (size_t)n * NH * sizeof(float);
    int*   cnt     = (int*)w;                   w += (size_t)n * sizeof(int);
    int*   partial = (int*)w;                   w += (size_t)n * sizeof(int);
    int*   bsum    = (int*)w;                   w += 256 * sizeof(int);
    int*   starts  = (int*)w;                   w += (size_t)(n + 1) * sizeof(int);
    int*   cursor  = (int*)w;                   w += (size_t)n * sizeof(int);
    int*   srcperm = (int*)w;                   w += (size_t)ne * sizeof(int);

    hipMemsetAsync(cnt, 0, (size_t)n * sizeof(int), stream);

    gemm_xw_fused<<<(n + 15) / 16, 256, 0, stream>>>(x, W, att_src, att_dst,
                                                     xw, a_src, a_dst, n);

    hist_dst<<<(ne + 255) / 256, 256, 0, stream>>>(dst, cnt, ne);
    scanA<<<nb, 256, 0, stream>>>(cnt, partial, bsum, n);
    scanB<<<1, 256, 0, stream>>>(bsum, nb);
    scanC<<<nb, 256, 0, stream>>>(partial, bsum, starts, cursor, n, ne);
    scatter_edges<<<(ne + 255) / 256, 256, 0, stream>>>(src, dst, cursor, srcperm, ne);

    node_agg<<<((size_t)n * 64 + 255) / 256, 256, 0, stream>>>(
        srcperm, starts, a_src, a_dst, (const uint4*)xw, x, bias, gamma, beta, out, n);
}

// Round 4
// 264.585 us; speedup vs baseline: 2.5821x; 1.2823x over previous
//
#include <hip/hip_runtime.h>
#include <hip/hip_bf16.h>
#include <math.h>

#define ND 128      // feature dim D
#define NH 4        // heads
#define HD 512      // H*D

typedef __attribute__((ext_vector_type(8))) short bf16x8;
typedef __attribute__((ext_vector_type(4))) float f32x4;

__device__ __forceinline__ unsigned pack_bf16(float a, float b) {
    unsigned ua = __float_as_uint(a), ub = __float_as_uint(b);
    ua = (ua + 0x7fffu + ((ua >> 16) & 1u)) >> 16;
    ub = (ub + 0x7fffu + ((ub >> 16) & 1u)) >> 16;
    return ua | (ub << 16);
}
__device__ __forceinline__ unsigned short bf16r(float a) {
    unsigned ua = __float_as_uint(a);
    return (unsigned short)((ua + 0x7fffu + ((ua >> 16) & 1u)) >> 16);
}
__device__ __forceinline__ float bflo(unsigned u) { return __uint_as_float(u << 16); }
__device__ __forceinline__ float bfhi(unsigned u) { return __uint_as_float(u & 0xffff0000u); }

// ---------------------------------------------------------------------------
// K0: transpose W [128][512] fp32 -> Wt [512][128] bf16 (once, tiny).
// ---------------------------------------------------------------------------
__global__ __launch_bounds__(256) void prep_wt(const float* __restrict__ W,
                                               unsigned short* __restrict__ Wt) {
    int idx = blockIdx.x * 256 + threadIdx.x;   // over 512*128
    int nl = idx >> 7, k = idx & 127;
    Wt[idx] = bf16r(W[(size_t)k * HD + nl]);
}

// ---------------------------------------------------------------------------
// K1: MFMA GEMM. Block = 128 rows x 128 cols (one head), 4 waves.
// A: x fp32 -> bf16 LDS (swizzled). B: Wt bf16 -> LDS (swizzled).
// Wave w owns rows 32w..32w+31: M_rep=2, N_rep=8, 4 ksteps of 32.
// Epilogue: fp32 attention dots from acc + bf16 xw store.
// Fragment layouts (mfma_f32_16x16x32_bf16):
//   A: row=lane%16, k=8*(lane/16)+e ; B: col=lane%16, same k
//   C/D: col=lane&15, row=(lane>>4)*4+reg
// ---------------------------------------------------------------------------
__global__ __launch_bounds__(256, 2) void gemm_mfma(
        const float* __restrict__ x, const unsigned short* __restrict__ Wt,
        const float* __restrict__ att_src, const float* __restrict__ att_dst,
        unsigned short* __restrict__ xw, float* __restrict__ a_src,
        float* __restrict__ a_dst, int n) {
    __shared__ char lds[65536];
    char* As = lds;            // 128 rows x 128 k bf16, swizzled
    char* Bs = lds + 32768;    // 128 n   x 128 k bf16, swizzled
    const int t = threadIdx.x;
    const int row0 = blockIdx.x * 128;
    const int h = blockIdx.y;
    const int l = t & 63, w = t >> 6;
    const int eid = l & 15, g = l >> 4;

    // stage A
#pragma unroll
    for (int i = 0; i < 8; ++i) {
        int c = t + i * 256;
        int m = c >> 4, kb = c & 15;
        int row = row0 + m;
        uint4 pk;
        if (row < n) {
            const float4* xp = (const float4*)(x + (size_t)row * ND + kb * 8);
            float4 f0 = xp[0], f1 = xp[1];
            pk.x = pack_bf16(f0.x, f0.y); pk.y = pack_bf16(f0.z, f0.w);
            pk.z = pack_bf16(f1.x, f1.y); pk.w = pack_bf16(f1.z, f1.w);
        } else { pk.x = pk.y = pk.z = pk.w = 0u; }
        *(uint4*)(As + m * 256 + ((kb * 16) ^ ((m & 7) << 4))) = pk;
    }
    // stage B
#pragma unroll
    for (int i = 0; i < 8; ++i) {
        int c = t + i * 256;
        int nl = c >> 4, kb = c & 15;
        uint4 pv = *(const uint4*)(Wt + (size_t)(h * 128 + nl) * 128 + kb * 8);
        *(uint4*)(Bs + nl * 256 + ((kb * 16) ^ ((nl & 7) << 4))) = pv;
    }
    __syncthreads();

    f32x4 acc[2][8];
#pragma unroll
    for (int mt = 0; mt < 2; ++mt)
#pragma unroll
        for (int nr = 0; nr < 8; ++nr) acc[mt][nr] = (f32x4){0.f, 0.f, 0.f, 0.f};

    const int swz = (eid & 7) << 4;
#pragma unroll
    for (int ks = 0; ks < 4; ++ks) {
        int koff = (ks * 64 + g * 16) ^ swz;
        bf16x8 a0 = *(const bf16x8*)(As + (w * 32 + eid) * 256 + koff);
        bf16x8 a1 = *(const bf16x8*)(As + (w * 32 + 16 + eid) * 256 + koff);
#pragma unroll
        for (int nr = 0; nr < 8; ++nr) {
            bf16x8 b = *(const bf16x8*)(Bs + (nr * 16 + eid) * 256 + koff);
            acc[0][nr] = __builtin_amdgcn_mfma_f32_16x16x32_bf16(a0, b, acc[0][nr], 0, 0, 0);
            acc[1][nr] = __builtin_amdgcn_mfma_f32_16x16x32_bf16(a1, b, acc[1][nr], 0, 0, 0);
        }
    }

    // epilogue A: attention dots from fp32 acc
    float asv[8], adv[8];
#pragma unroll
    for (int nr = 0; nr < 8; ++nr) {
        asv[nr] = att_src[h * ND + nr * 16 + eid];
        adv[nr] = att_dst[h * ND + nr * 16 + eid];
    }
#pragma unroll
    for (int mt = 0; mt < 2; ++mt) {
#pragma unroll
        for (int ri = 0; ri < 4; ++ri) {
            float s = 0.f, d = 0.f;
#pragma unroll
            for (int nr = 0; nr < 8; ++nr) {
                s += acc[mt][nr][ri] * asv[nr];
                d += acc[mt][nr][ri] * adv[nr];
            }
#pragma unroll
            for (int off = 1; off < 16; off <<= 1) {
                s += __shfl_xor(s, off);
                d += __shfl_xor(d, off);
            }
            int row = row0 + w * 32 + mt * 16 + g * 4 + ri;
            if (eid == 0 && row < n) {
                a_src[(size_t)row * NH + h] = s;
                a_dst[(size_t)row * NH + h] = d;
            }
        }
    }

    // epilogue B: bf16 xw store
#pragma unroll
    for (int mt = 0; mt < 2; ++mt)
#pragma unroll
        for (int ri = 0; ri < 4; ++ri) {
            int row = row0 + w * 32 + mt * 16 + g * 4 + ri;
            if (row < n) {
#pragma unroll
                for (int nr = 0; nr < 8; ++nr)
                    xw[(size_t)row * HD + h * ND + nr * 16 + eid] = bf16r(acc[mt][nr][ri]);
            }
        }
}

// ---------------------------------------------------------------------------
// Counting sort of edges by dst: hist -> scan (3 kernels) -> scatter.
// ---------------------------------------------------------------------------
__global__ __launch_bounds__(256) void hist_dst(const int* __restrict__ dst,
                                                int* __restrict__ cnt, int ne) {
    int e = blockIdx.x * 256 + threadIdx.x;
    if (e < ne) atomicAdd(&cnt[dst[e]], 1);
}

__global__ __launch_bounds__(256) void scanA(const int* __restrict__ cnt,
                                             int* __restrict__ partial,
                                             int* __restrict__ bsum, int n) {
    __shared__ int sh[256];
    int gid = blockIdx.x * 256 + threadIdx.x;
    int v = (gid < n) ? cnt[gid] : 0;
    int val = v;
    sh[threadIdx.x] = val;
    __syncthreads();
#pragma unroll
    for (int off = 1; off < 256; off <<= 1) {
        int add = (threadIdx.x >= off) ? sh[threadIdx.x - off] : 0;
        __syncthreads();
        val += add;
        sh[threadIdx.x] = val;
        __syncthreads();
    }
    if (gid < n) partial[gid] = val - v;
    if (threadIdx.x == 255) bsum[blockIdx.x] = val;
}

__global__ __launch_bounds__(256) void scanB(int* __restrict__ bsum, int nb) {
    __shared__ int sh[256];
    int t = threadIdx.x;
    int v = (t < nb) ? bsum[t] : 0;
    int val = v;
    sh[t] = val;
    __syncthreads();
#pragma unroll
    for (int off = 1; off < 256; off <<= 1) {
        int add = (t >= off) ? sh[t - off] : 0;
        __syncthreads();
        val += add;
        sh[t] = val;
        __syncthreads();
    }
    if (t < nb) bsum[t] = val - v;
}

__global__ __launch_bounds__(256) void scanC(const int* __restrict__ partial,
                                             const int* __restrict__ bsum,
                                             int* __restrict__ starts,
                                             int* __restrict__ cursor, int n, int ne) {
    int gid = blockIdx.x * 256 + threadIdx.x;
    if (gid < n) {
        int s = partial[gid] + bsum[blockIdx.x];
        starts[gid] = s;
        cursor[gid] = s;
    }
    if (gid == 0) starts[n] = ne;
}

__global__ __launch_bounds__(256) void scatter_edges(const int* __restrict__ src,
                                                     const int* __restrict__ dst,
                                                     int* __restrict__ cursor,
                                                     int* __restrict__ srcperm, int ne) {
    int e = blockIdx.x * 256 + threadIdx.x;
    if (e < ne) {
        int pos = atomicAdd(&cursor[dst[e]], 1);
        srcperm[pos] = src[e];
    }
}

// ---------------------------------------------------------------------------
// K_agg: one wave per dst node. 16-edge chunks; lane = (head=l>>4, slot=l&15).
// Each lane computes its own head's exp for its slot's edge (1 shfl each to
// broadcast src + weight). Gather loop unrolled x4 for 4 loads in flight.
// ---------------------------------------------------------------------------
#define ACC8(vv, ww)                                                      \
    acc[0] = fmaf(ww, bflo(vv.x), acc[0]);                                \
    acc[1] = fmaf(ww, bfhi(vv.x), acc[1]);                                \
    acc[2] = fmaf(ww, bflo(vv.y), acc[2]);                                \
    acc[3] = fmaf(ww, bfhi(vv.y), acc[3]);                                \
    acc[4] = fmaf(ww, bflo(vv.z), acc[4]);                                \
    acc[5] = fmaf(ww, bfhi(vv.z), acc[5]);                                \
    acc[6] = fmaf(ww, bflo(vv.w), acc[6]);                                \
    acc[7] = fmaf(ww, bfhi(vv.w), acc[7]);

__global__ __launch_bounds__(256) void node_agg(const int* __restrict__ srcperm,
                                                const int* __restrict__ starts,
                                                const float* __restrict__ a_src,
                                                const float* __restrict__ a_dst,
                                                const uint4* __restrict__ xw,
                                                const float* __restrict__ x,
                                                const float* __restrict__ bias,
                                                const float* __restrict__ gamma,
                                                const float* __restrict__ beta,
                                                float* __restrict__ out, int n) {
    int node = (blockIdx.x * 256 + threadIdx.x) >> 6;
    int lane = threadIdx.x & 63;
    if (node >= n) return;
    const int hgrp = lane >> 4;   // my head
    const int eid = lane & 15;    // my edge slot / feature octet

    int s0 = starts[node], s1 = starts[node + 1];
    float ad_m = a_dst[(size_t)node * NH + hgrp];

    float den = 0.f;
    float acc[8];
#pragma unroll
    for (int j = 0; j < 8; ++j) acc[j] = 0.f;

    for (int base = s0; base < s1; base += 16) {
        int rem = s1 - base; if (rem > 16) rem = 16;
        int sl = 0; float em = 0.f;
        if (eid < rem) {
            sl = srcperm[base + eid];
            float A = a_src[(size_t)sl * NH + hgrp] + ad_m;
            A = (A > 0.f) ? A : 0.2f * A;
            em = expf(A);
        }
        den += em;

        int jj = 0;
        for (; jj + 4 <= rem; jj += 4) {
            int t0 = __shfl(sl, jj),     t1 = __shfl(sl, jj + 1);
            int t2 = __shfl(sl, jj + 2), t3 = __shfl(sl, jj + 3);
            uint4 v0 = xw[(size_t)t0 * 64 + lane];
            uint4 v1 = xw[(size_t)t1 * 64 + lane];
            uint4 v2 = xw[(size_t)t2 * 64 + lane];
            uint4 v3 = xw[(size_t)t3 * 64 + lane];
            float w0 = __shfl(em, (hgrp << 4) + jj);
            float w1 = __shfl(em, (hgrp << 4) + jj + 1);
            float w2 = __shfl(em, (hgrp << 4) + jj + 2);
            float w3 = __shfl(em, (hgrp << 4) + jj + 3);
            ACC8(v0, w0); ACC8(v1, w1); ACC8(v2, w2); ACC8(v3, w3);
        }
        for (; jj < rem; ++jj) {
            int ts = __shfl(sl, jj);
            uint4 v = xw[(size_t)ts * 64 + lane];
            float ww = __shfl(em, (hgrp << 4) + jj);
            ACC8(v, ww);
        }
    }

    // per-head denominator: reduce over the 16 slots in my head group
#pragma unroll
    for (int off = 1; off < 16; off <<= 1) den += __shfl_xor(den, off);
    float imy = (den > 0.f) ? 0.25f / den : 0.f;

    float v[8];
#pragma unroll
    for (int j = 0; j < 8; ++j) {
        v[j] = acc[j] * imy;
        v[j] += __shfl_xor(v[j], 16);   // sum over heads
        v[j] += __shfl_xor(v[j], 32);
    }

    const float4* bp = (const float4*)(bias + eid * 8);
    float4 b0 = bp[0], b1 = bp[1];
    v[0] += b0.x; v[1] += b0.y; v[2] += b0.z; v[3] += b0.w;
    v[4] += b1.x; v[5] += b1.y; v[6] += b1.z; v[7] += b1.w;

    // LayerNorm over 128 features = 16 lane-groups x 8 slots (replicated 4x)
    float s = 0.f, s2 = 0.f;
#pragma unroll
    for (int j = 0; j < 8; ++j) { s += v[j]; s2 += v[j] * v[j]; }
#pragma unroll
    for (int off = 1; off < 16; off <<= 1) {
        s += __shfl_xor(s, off);
        s2 += __shfl_xor(s2, off);
    }
    float mu = s * (1.0f / ND);
    float var = s2 * (1.0f / ND) - mu * mu;
    var = fmaxf(var, 0.0f);
    float inv = rsqrtf(var + 1e-5f);

    const float4* gp = (const float4*)(gamma + eid * 8);
    const float4* btp = (const float4*)(beta + eid * 8);
    float4 g0 = gp[0], g1 = gp[1];
    float4 t0 = btp[0], t1 = btp[1];
    float gm[8] = {g0.x, g0.y, g0.z, g0.w, g1.x, g1.y, g1.z, g1.w};
    float bt[8] = {t0.x, t0.y, t0.z, t0.w, t1.x, t1.y, t1.z, t1.w};

    float y[8];
#pragma unroll
    for (int j = 0; j < 8; ++j) {
        float yn = (v[j] - mu) * inv * gm[j] + bt[j];
        y[j] = 0.5f * yn * (1.0f + erff(yn * 0.70710678118654752f));
    }

    if (lane < 16) {   // one replica writes; +residual
        const float4* xp = (const float4*)(x + (size_t)node * ND + eid * 8);
        float4 r0 = xp[0], r1 = xp[1];
        float4 o0 = {y[0] + r0.x, y[1] + r0.y, y[2] + r0.z, y[3] + r0.w};
        float4 o1 = {y[4] + r1.x, y[5] + r1.y, y[6] + r1.z, y[7] + r1.w};
        float4* op = (float4*)(out + (size_t)node * ND + eid * 8);
        op[0] = o0; op[1] = o1;
    }
}

// ---------------------------------------------------------------------------
extern "C" void kernel_launch(void* const* d_in, const int* in_sizes, int n_in,
                              void* d_out, int out_size, void* d_ws, size_t ws_size,
                              hipStream_t stream) {
    const float* x       = (const float*)d_in[0];
    const int*   edge    = (const int*)d_in[1];   // [2, E]: src row then dst row
    const float* W       = (const float*)d_in[2];
    const float* att_src = (const float*)d_in[3];
    const float* att_dst = (const float*)d_in[4];
    const float* bias    = (const float*)d_in[5];
    const float* gamma   = (const float*)d_in[6];
    const float* beta    = (const float*)d_in[7];
    float* out = (float*)d_out;

    const int n  = in_sizes[0] / ND;   // 50000
    const int ne = in_sizes[1] / 2;    // 800000
    const int* src = edge;
    const int* dst = edge + ne;

    const int nb = (n + 255) / 256;

    char* wsp = (char*)d_ws;
    unsigned short* xw = (unsigned short*)wsp;  wsp += (size_t)n * HD * sizeof(short);
    unsigned short* Wt = (unsigned short*)wsp;  wsp += (size_t)HD * ND * sizeof(short);
    float* a_src   = (float*)wsp;               wsp += (size_t)n * NH * sizeof(float);
    float* a_dst   = (float*)wsp;               wsp += (size_t)n * NH * sizeof(float);
    int*   cnt     = (int*)wsp;                 wsp += (size_t)n * sizeof(int);
    int*   partial = (int*)wsp;                 wsp += (size_t)n * sizeof(int);
    int*   bsum    = (int*)wsp;                 wsp += 256 * sizeof(int);
    int*   starts  = (int*)wsp;                 wsp += (size_t)(n + 1) * sizeof(int);
    int*   cursor  = (int*)wsp;                 wsp += (size_t)n * sizeof(int);
    int*   srcperm = (int*)wsp;                 wsp += (size_t)ne * sizeof(int);

    hipMemsetAsync(cnt, 0, (size_t)n * sizeof(int), stream);

    prep_wt<<<(HD * ND) / 256, 256, 0, stream>>>(W, Wt);

    dim3 ggrid((n + 127) / 128, NH);
    gemm_mfma<<<ggrid, 256, 0, stream>>>(x, Wt, att_src, att_dst, xw, a_src, a_dst, n);

    hist_dst<<<(ne + 255) / 256, 256, 0, stream>>>(dst, cnt, ne);
    scanA<<<nb, 256, 0, stream>>>(cnt, partial, bsum, n);
    scanB<<<1, 256, 0, stream>>>(bsum, nb);
    scanC<<<nb, 256, 0, stream>>>(partial, bsum, starts, cursor, n, ne);
    scatter_edges<<<(ne + 255) / 256, 256, 0, stream>>>(src, dst, cursor, srcperm, ne);

    node_agg<<<((size_t)n * 64 + 255) / 256, 256, 0, stream>>>(
        srcperm, starts, a_src, a_dst, (const uint4*)xw, x, bias, gamma, beta, out, n);
}